// Round 1
// baseline (468.443 us; speedup 1.0000x reference)
//
#include <hip/hip_runtime.h>

#define B_  4
#define T_  8192
#define E_  1024
#define DK_ 128

typedef __attribute__((ext_vector_type(8))) _Float16 half8;
typedef __attribute__((ext_vector_type(4))) float float4v;

__device__ __forceinline__ half8 cvt8h(float4 a, float4 b) {
    half8 r;
    r[0] = (_Float16)a.x; r[1] = (_Float16)a.y; r[2] = (_Float16)a.z; r[3] = (_Float16)a.w;
    r[4] = (_Float16)b.x; r[5] = (_Float16)b.y; r[6] = (_Float16)b.z; r[7] = (_Float16)b.w;
    return r;
}

// One-time W(fp32) -> fp16 pre-convert into workspace, laid out exactly as the
// per-k-chunk staging tiles: W16[ki][row][64], ki = k/64, row: 0-127 Q, 128-255 K, 256-383 V.
__global__ void wconv(const float* __restrict__ Wk, const float* __restrict__ Wq,
                      const float* __restrict__ Wv, ushort* __restrict__ W16) {
    const int g   = blockIdx.x * 256 + threadIdx.x; // [0, 49152)
    const int c   = g & 7;
    const int ki  = (g >> 3) & 15;
    const int row = g >> 7;                          // [0, 384)
    const float* src = (row < 128) ? (Wq + (size_t)row * E_)
                     : (row < 256) ? (Wk + (size_t)(row - 128) * E_)
                                   : (Wv + (size_t)(row - 256) * E_);
    src += ki * 64 + c * 8;
    *(half8*)(W16 + (size_t)(ki * 384 + row) * 64 + c * 8) =
        cvt8h(*(const float4*)src, *(const float4*)(src + 4));
}

// One block per (b, s): fused fp16-MFMA QKV projection + fp32 attention.
// 512 threads = 8 waves. Projection: M=64 tokens, N=384 (Q|K|V), K=1024, BK=64.
// Phase 1: depth-2 register pipeline, double-buffered LDS, ONE barrier per iter.
__global__ __launch_bounds__(512, 2)
void dilattn(const float* __restrict__ x_in, const float* __restrict__ P,
             const ushort* __restrict__ W16, float* __restrict__ out)
{
    // 129 KB LDS: staging xs[2][64][72] + ws[2][384][72] (fp16);
    // attention regions alias the same memory after phase 1.
    __shared__ __align__(16) ushort sh[2 * 64 * 72 + 2 * 384 * 72];
    ushort* xs0   = sh;                 // [2][64*72]
    ushort* ws0   = sh + 2 * 64 * 72;   // [2][384*72]
    float*  lds_f = (float*)sh;
    constexpr int A_OFF = 0;
    constexpr int B_OFF = 8192;
    constexpr int S_OFF = 8192;
    const float NORMF = 0.08838834764831845f; // 1/sqrt(128)

    const int tid  = threadIdx.x;
    const int lane = tid & 63;
    const int w    = __builtin_amdgcn_readfirstlane(tid >> 6); // 0..7
    const int b    = blockIdx.x >> 6;
    const int s    = blockIdx.x & 63;

    const int lr   = lane & 15;   // in-tile 16-dim index
    const int lg   = lane >> 4;   // k-group 0..3
    const int mt   = w & 3;       // M-tile
    const int half = w >> 2;      // N-half

    // staging assignment: thread -> (row, 8-elem chunk)
    const int c8 = tid & 7;
    const int xr = tid >> 3;
    const float*  xrow  = x_in + ((size_t)b * T_ + 128 * xr + s) * E_ + c8 * 8;
    const ushort* wbase = W16 + xr * 64 + c8 * 8;

    float4v acc[12];
#pragma unroll
    for (int j = 0; j < 12; ++j) acc[j] = (float4v){0.f, 0.f, 0.f, 0.f};

    uint4  wr[2][6];   // W stage regs (fp16, no cvt needed)
    float4 xa[2][2];   // x stage regs (fp32 -> cvt at write)

#define ISSUE_STAGE(K, SL) { \
    _Pragma("unroll") \
    for (int p = 0; p < 6; ++p) wr[SL][p] = *(const uint4*)(wbase + (K) * 24576 + p * 4096); \
    xa[SL][0] = *(const float4*)(xrow + (K) * 64); \
    xa[SL][1] = *(const float4*)(xrow + (K) * 64 + 4); }

#define WRITE_STAGE(K, SL) { \
    const int wb_ = ((K) & 1) * (384 * 72); \
    _Pragma("unroll") \
    for (int p = 0; p < 6; ++p) *(uint4*)&ws0[wb_ + (xr + 64 * p) * 72 + c8 * 8] = wr[SL][p]; \
    *(half8*)&xs0[((K) & 1) * (64 * 72) + xr * 72 + c8 * 8] = cvt8h(xa[SL][0], xa[SL][1]); }

    // ---------------- Phase 1: QKV projection via MFMA ----------------
    ISSUE_STAGE(0, 0);
    ISSUE_STAGE(1, 1);
    WRITE_STAGE(0, 0);     // waits only on stage-0 loads (stage-1 stays in flight)
    __syncthreads();

#pragma unroll
    for (int k = 0; k < 16; ++k) {
        if (k < 14) ISSUE_STAGE(k + 2, k & 1);        // depth-2 prefetch
        if (k < 15) WRITE_STAGE(k + 1, (k + 1) & 1);  // fill the other buffer
        const int xb = (k & 1) * (64 * 72);
        const int wb = (k & 1) * (384 * 72);
#pragma unroll
        for (int kk = 0; kk < 2; ++kk) {
            const half8 afr = *(const half8*)&xs0[xb + (mt * 16 + lr) * 72 + kk * 32 + lg * 8];
#pragma unroll
            for (int j = 0; j < 12; ++j) {
                const half8 bfr = *(const half8*)&ws0[wb + ((half * 12 + j) * 16 + lr) * 72 + kk * 32 + lg * 8];
                acc[j] = __builtin_amdgcn_mfma_f32_16x16x32_f16(afr, bfr, acc[j], 0, 0, 0);
            }
        }
        __syncthreads(); // publishes stage k+1; guards buffer reuse next iter
    }

    // ------- scatter C fragments: Q -> A region (swizzled), K -> B region (rotated K^T) -------
    // C layout: row l = mt*16 + lg*4 + reg (token), col n = nt*16 + lr (out dim)
    const int rbase = mt * 16 + lg * 4;
#pragma unroll
    for (int j = 0; j < 12; ++j) {
        const int nt = half * 12 + j;
        const int n  = nt * 16 + lr;
        if (nt < 8) {        // Q
#pragma unroll
            for (int r = 0; r < 4; ++r) {
                const int l = rbase + r;
                lds_f[A_OFF + l * 128 + ((n + 4 * l) & 127)] = acc[j][r];
            }
        } else if (nt < 16) { // K^T, rotated by m to avoid write conflicts
            const int m = n - 128;
#pragma unroll
            for (int r = 0; r < 4; ++r) {
                const int l = rbase + r;
                lds_f[B_OFF + m * 64 + ((l + m) & 63)] = acc[j][r];
            }
        } // V tiles (nt>=16) stay in registers until after phase 2a
    }
    __syncthreads();

    // ---------------- Phase 2a: S[k][q] = sum_m K[k][m]*Q[q][m]; k = lane ----------------
    // prefetch scattered P bias (L2-resident after block 0)
    float pb[8];
#pragma unroll
    for (int i = 0; i < 8; ++i)
        pb[i] = P[(size_t)lane * ((size_t)128 * T_) + (size_t)(w * 8 + i) * 128];

    float sd[8];
#pragma unroll
    for (int i = 0; i < 8; ++i) sd[i] = 0.f;

    for (int m4 = 0; m4 < 32; ++m4) {
        const int mm = 4 * m4;
        const float k0 = lds_f[B_OFF + (mm + 0) * 64 + ((lane + mm + 0) & 63)];
        const float k1 = lds_f[B_OFF + (mm + 1) * 64 + ((lane + mm + 1) & 63)];
        const float k2 = lds_f[B_OFF + (mm + 2) * 64 + ((lane + mm + 2) & 63)];
        const float k3 = lds_f[B_OFF + (mm + 3) * 64 + ((lane + mm + 3) & 63)];
#pragma unroll
        for (int i = 0; i < 8; ++i) {
            const int q = w * 8 + i; // wave-uniform -> broadcast read
            const float4 qv = *(const float4*)&lds_f[A_OFF + q * 128 + ((4 * (m4 + q)) & 127)];
            sd[i] = fmaf(k0, qv.x, fmaf(k1, qv.y, fmaf(k2, qv.z, fmaf(k3, qv.w, sd[i]))));
        }
    }
    __syncthreads(); // all Q/K^T reads done; A and B regions reusable

    // V fragments -> A region (half==1 waves hold V tiles in acc[4..11])
    if (half == 1) {
#pragma unroll
        for (int j = 4; j < 12; ++j) {
            const int nt = 12 + j;
            const int m  = nt * 16 + lr - 256; // V column 0..127
#pragma unroll
            for (int r = 0; r < 4; ++r) {
                const int l = rbase + r;
                lds_f[A_OFF + l * 128 + ((m + 4 * l) & 127)] = acc[j][r];
            }
        }
    }

    // ---------------- wave-parallel in-register softmax ----------------
    // (w,i) owns column q = w*8+i; k = lane. Fold 1/sum into stored p.
#pragma unroll
    for (int i = 0; i < 8; ++i) {
        const int q = w * 8 + i;
        const float logit = ((lane >= q ? sd[i] : -10000.f) + pb[i]) * NORMF;
        float mx = logit;
#pragma unroll
        for (int off = 32; off >= 1; off >>= 1) mx = fmaxf(mx, __shfl_xor(mx, off));
        const float ev = __expf(logit - mx);
        float sum = ev;
#pragma unroll
        for (int off = 32; off >= 1; off >>= 1) sum += __shfl_xor(sum, off);
        lds_f[S_OFF + lane * 65 + q] = ev * (1.0f / sum);
    }
    __syncthreads();

    // ---------------- Phase 2b: O[q][m] = sum_k p[k][q] * V[k][m] ----------------
    float4 o0 = {0,0,0,0}, o1 = {0,0,0,0}, o2 = {0,0,0,0}, o3 = {0,0,0,0};
    for (int k = 0; k < 64; ++k) {
        const float p = lds_f[S_OFF + k * 65 + lane];
        const int base = A_OFF + k * 128;
        const float4 v0 = *(const float4*)&lds_f[base + ((16 * w + 0  + 4 * k) & 127)];
        const float4 v1 = *(const float4*)&lds_f[base + ((16 * w + 4  + 4 * k) & 127)];
        const float4 v2 = *(const float4*)&lds_f[base + ((16 * w + 8  + 4 * k) & 127)];
        const float4 v3 = *(const float4*)&lds_f[base + ((16 * w + 12 + 4 * k) & 127)];
        o0.x = fmaf(p, v0.x, o0.x); o0.y = fmaf(p, v0.y, o0.y); o0.z = fmaf(p, v0.z, o0.z); o0.w = fmaf(p, v0.w, o0.w);
        o1.x = fmaf(p, v1.x, o1.x); o1.y = fmaf(p, v1.y, o1.y); o1.z = fmaf(p, v1.z, o1.z); o1.w = fmaf(p, v1.w, o1.w);
        o2.x = fmaf(p, v2.x, o2.x); o2.y = fmaf(p, v2.y, o2.y); o2.z = fmaf(p, v2.z, o2.z); o2.w = fmaf(p, v2.w, o2.w);
        o3.x = fmaf(p, v3.x, o3.x); o3.y = fmaf(p, v3.y, o3.y); o3.z = fmaf(p, v3.z, o3.z); o3.w = fmaf(p, v3.w, o3.w);
    }
    float* orow = out + ((size_t)b * T_ + (size_t)(2 * (s * 64 + lane))) * DK_ + w * 16;
    *(float4*)(orow + 0)  = o0;
    *(float4*)(orow + 4)  = o1;
    *(float4*)(orow + 8)  = o2;
    *(float4*)(orow + 12) = o3;
    // odd output row (token t+1) is zero: write it here instead of a memset dispatch
    const float4 z = {0.f, 0.f, 0.f, 0.f};
    *(float4*)(orow + DK_ + 0)  = z;
    *(float4*)(orow + DK_ + 4)  = z;
    *(float4*)(orow + DK_ + 8)  = z;
    *(float4*)(orow + DK_ + 12) = z;
}

extern "C" void kernel_launch(void* const* d_in, const int* in_sizes, int n_in,
                              void* d_out, int out_size, void* d_ws, size_t ws_size,
                              hipStream_t stream) {
    (void)in_sizes; (void)n_in; (void)out_size; (void)ws_size;
    const float* x_in = (const float*)d_in[0];
    const float* P    = (const float*)d_in[1];
    const float* Wk   = (const float*)d_in[2];  // dict order: Wk before Wq
    const float* Wq   = (const float*)d_in[3];
    const float* Wv   = (const float*)d_in[4];
    float* out = (float*)d_out;
    ushort* W16 = (ushort*)d_ws;                // needs 384*1024*2 = 768 KB of workspace

    wconv<<<dim3(192), dim3(256), 0, stream>>>(Wk, Wq, Wv, W16);
    dilattn<<<dim3(256), dim3(512), 0, stream>>>(x_in, P, W16, out);
}

// Round 2
// 468.058 us; speedup vs baseline: 1.0008x; 1.0008x over previous
//
#include <hip/hip_runtime.h>

#define B_  4
#define T_  8192
#define E_  1024
#define DK_ 128

typedef __attribute__((ext_vector_type(8))) _Float16 half8;
typedef __attribute__((ext_vector_type(4))) float float4v;

__device__ __forceinline__ half8 cvt8h(float4 a, float4 b) {
    half8 r;
    r[0] = (_Float16)a.x; r[1] = (_Float16)a.y; r[2] = (_Float16)a.z; r[3] = (_Float16)a.w;
    r[4] = (_Float16)b.x; r[5] = (_Float16)b.y; r[6] = (_Float16)b.z; r[7] = (_Float16)b.w;
    return r;
}

// One-time W(fp32) -> fp16 pre-convert into workspace, laid out exactly as the
// per-k-chunk staging tiles: W16[ki][row][64], ki = k/64, row: 0-127 Q, 128-255 K, 256-383 V.
__global__ void wconv(const float* __restrict__ Wk, const float* __restrict__ Wq,
                      const float* __restrict__ Wv, ushort* __restrict__ W16) {
    const int g   = blockIdx.x * 256 + threadIdx.x; // [0, 49152)
    const int c   = g & 7;
    const int ki  = (g >> 3) & 15;
    const int row = g >> 7;                          // [0, 384)
    const float* src = (row < 128) ? (Wq + (size_t)row * E_)
                     : (row < 256) ? (Wk + (size_t)(row - 128) * E_)
                                   : (Wv + (size_t)(row - 256) * E_);
    src += ki * 64 + c * 8;
    *(half8*)(W16 + (size_t)(ki * 384 + row) * 64 + c * 8) =
        cvt8h(*(const float4*)src, *(const float4*)(src + 4));
}

// One block per (b, s): fused fp16-MFMA QKV projection + fp32 attention.
// 512 threads = 8 waves. Projection: M=64 tokens, N=384 (Q|K|V), K=1024, BK=64.
// Wave w: M-tile mt=w&3, N-half=w>>2 (12 N-tiles each). 48 fp32 accumulators/wave.
// Phase-1 structure identical to the harness-verified 434 µs kernel; W staged
// pre-converted (fp16) from workspace, so no per-iteration cvt for W.
__global__ __launch_bounds__(512, 2)
void dilattn(const float* __restrict__ x_in, const float* __restrict__ P,
             const ushort* __restrict__ W16, float* __restrict__ out)
{
    // 64 KB LDS, aliased:
    //  staging:   xs f16[64][72] (9216 B) | wsm f16[384][72] (55296 B)
    //  attention: A region floats [0,8192) = Q (swizzled) then V; B region [8192,16384) = K^T (rotated) then S
    __shared__ float lds_f[16384];
    ushort* xs  = (ushort*)lds_f;        // [64][72]
    ushort* wsm = xs + 64 * 72;          // [384][72]
    constexpr int A_OFF = 0;
    constexpr int B_OFF = 8192;
    constexpr int S_OFF = 8192;
    const float NORMF = 0.08838834764831845f; // 1/sqrt(128)

    const int tid  = threadIdx.x;
    const int lane = tid & 63;
    const int w    = __builtin_amdgcn_readfirstlane(tid >> 6); // 0..7
    const int b    = blockIdx.x >> 6;
    const int s    = blockIdx.x & 63;

    const int lr   = lane & 15;   // in-tile 16-dim index
    const int lg   = lane >> 4;   // k-group 0..3
    const int mt   = w & 3;       // M-tile
    const int half = w >> 2;      // N-half

    // ------- staging assignment: thread -> (row, 8-elem chunk) -------
    const int c8 = tid & 7;       // chunk 0..7 (8 elems each, BK=64)
    const int xr = tid >> 3;      // row 0..63
    const float*  xrow = x_in + ((size_t)b * T_ + 128 * xr + s) * E_ + c8 * 8;
    const ushort* wrow = W16 + xr * 64 + c8 * 8; // + ki*24576 + p*4096

    float4v acc[12];
#pragma unroll
    for (int j = 0; j < 12; ++j) acc[j] = (float4v){0.f, 0.f, 0.f, 0.f};

    // ---------------- Phase 1: QKV projection via MFMA ----------------
    float4 xa0, xa1;
    uint4  wa[6];
    // preload iter 0
    xa0 = *(const float4*)(xrow);
    xa1 = *(const float4*)(xrow + 4);
#pragma unroll
    for (int p = 0; p < 6; ++p) wa[p] = *(const uint4*)(wrow + p * 4096);

    for (int ki = 0; ki < 16; ++ki) {
        __syncthreads(); // previous iter's LDS reads complete
        *(half8*)&xs[xr * 72 + c8 * 8] = cvt8h(xa0, xa1);
#pragma unroll
        for (int p = 0; p < 6; ++p)
            *(uint4*)&wsm[(xr + 64 * p) * 72 + c8 * 8] = wa[p];
        __syncthreads(); // tiles visible

        if (ki < 15) { // issue next iter's globals, overlap with MFMA
            const int k0 = (ki + 1) * 64;
            xa0 = *(const float4*)(xrow + k0);
            xa1 = *(const float4*)(xrow + k0 + 4);
            const int wk = (ki + 1) * 24576;
#pragma unroll
            for (int p = 0; p < 6; ++p)
                wa[p] = *(const uint4*)(wrow + wk + p * 4096);
        }

#pragma unroll
        for (int kk = 0; kk < 2; ++kk) {
            const half8 afr = *(const half8*)&xs[(mt * 16 + lr) * 72 + kk * 32 + lg * 8];
#pragma unroll
            for (int j = 0; j < 12; ++j) {
                const half8 bfr = *(const half8*)&wsm[((half * 12 + j) * 16 + lr) * 72 + kk * 32 + lg * 8];
                acc[j] = __builtin_amdgcn_mfma_f32_16x16x32_f16(afr, bfr, acc[j], 0, 0, 0);
            }
        }
    }
    __syncthreads(); // last MFMA reads done; staging LDS now dead

    // ------- scatter C fragments: Q -> A region (swizzled), K -> B region (rotated K^T) -------
    // C layout: row l = mt*16 + lg*4 + reg (token), col n = nt*16 + lr (out dim)
    const int rbase = mt * 16 + lg * 4;
#pragma unroll
    for (int j = 0; j < 12; ++j) {
        const int nt = half * 12 + j;
        const int n  = nt * 16 + lr;
        if (nt < 8) {        // Q
#pragma unroll
            for (int r = 0; r < 4; ++r) {
                const int l = rbase + r;
                lds_f[A_OFF + l * 128 + ((n + 4 * l) & 127)] = acc[j][r];
            }
        } else if (nt < 16) { // K^T, rotated by m to avoid write conflicts
            const int m = n - 128;
#pragma unroll
            for (int r = 0; r < 4; ++r) {
                const int l = rbase + r;
                lds_f[B_OFF + m * 64 + ((l + m) & 63)] = acc[j][r];
            }
        } // V tiles (nt>=16) stay in registers until after phase 2a
    }
    __syncthreads();

    // ---------------- Phase 2a: S[k][q] = sum_m K[k][m]*Q[q][m]; k = lane ----------------
    // prefetch scattered P bias (L3-resident); hides latency under the K.Q loop
    float pb[8];
#pragma unroll
    for (int i = 0; i < 8; ++i)
        pb[i] = P[(size_t)lane * ((size_t)128 * T_) + (size_t)(w * 8 + i) * 128];

    float sd[8];
#pragma unroll
    for (int i = 0; i < 8; ++i) sd[i] = 0.f;

    for (int m4 = 0; m4 < 32; ++m4) {
        const int mm = 4 * m4;
        const float k0 = lds_f[B_OFF + (mm + 0) * 64 + ((lane + mm + 0) & 63)];
        const float k1 = lds_f[B_OFF + (mm + 1) * 64 + ((lane + mm + 1) & 63)];
        const float k2 = lds_f[B_OFF + (mm + 2) * 64 + ((lane + mm + 2) & 63)];
        const float k3 = lds_f[B_OFF + (mm + 3) * 64 + ((lane + mm + 3) & 63)];
#pragma unroll
        for (int i = 0; i < 8; ++i) {
            const int q = w * 8 + i; // wave-uniform -> broadcast read
            const float4 qv = *(const float4*)&lds_f[A_OFF + q * 128 + ((4 * (m4 + q)) & 127)];
            sd[i] = fmaf(k0, qv.x, fmaf(k1, qv.y, fmaf(k2, qv.z, fmaf(k3, qv.w, sd[i]))));
        }
    }
    __syncthreads(); // all Q/K^T reads done; A and B regions reusable

    // V fragments -> A region (half==1 waves hold V tiles in acc[4..11])
    if (half == 1) {
#pragma unroll
        for (int j = 4; j < 12; ++j) {
            const int nt = 12 + j;
            const int m  = nt * 16 + lr - 256; // V column 0..127
#pragma unroll
            for (int r = 0; r < 4; ++r) {
                const int l = rbase + r;
                lds_f[A_OFF + l * 128 + ((m + 4 * l) & 127)] = acc[j][r];
            }
        }
    }

    // ---------------- wave-parallel in-register softmax ----------------
    // (w,i) owns column q = w*8+i; k = lane. Fold 1/sum into stored p.
#pragma unroll
    for (int i = 0; i < 8; ++i) {
        const int q = w * 8 + i;
        const float logit = ((lane >= q ? sd[i] : -10000.f) + pb[i]) * NORMF;
        float mx = logit;
#pragma unroll
        for (int off = 32; off >= 1; off >>= 1) mx = fmaxf(mx, __shfl_xor(mx, off));
        const float ev = __expf(logit - mx);
        float sum = ev;
#pragma unroll
        for (int off = 32; off >= 1; off >>= 1) sum += __shfl_xor(sum, off);
        lds_f[S_OFF + lane * 65 + q] = ev * (1.0f / sum);
    }
    __syncthreads();

    // ---------------- Phase 2b: O[q][m] = sum_k p[k][q] * V[k][m] ----------------
    float4 o0 = {0,0,0,0}, o1 = {0,0,0,0}, o2 = {0,0,0,0}, o3 = {0,0,0,0};
    for (int k = 0; k < 64; ++k) {
        const float p = lds_f[S_OFF + k * 65 + lane];
        const int base = A_OFF + k * 128;
        const float4 v0 = *(const float4*)&lds_f[base + ((16 * w + 0  + 4 * k) & 127)];
        const float4 v1 = *(const float4*)&lds_f[base + ((16 * w + 4  + 4 * k) & 127)];
        const float4 v2 = *(const float4*)&lds_f[base + ((16 * w + 8  + 4 * k) & 127)];
        const float4 v3 = *(const float4*)&lds_f[base + ((16 * w + 12 + 4 * k) & 127)];
        o0.x = fmaf(p, v0.x, o0.x); o0.y = fmaf(p, v0.y, o0.y); o0.z = fmaf(p, v0.z, o0.z); o0.w = fmaf(p, v0.w, o0.w);
        o1.x = fmaf(p, v1.x, o1.x); o1.y = fmaf(p, v1.y, o1.y); o1.z = fmaf(p, v1.z, o1.z); o1.w = fmaf(p, v1.w, o1.w);
        o2.x = fmaf(p, v2.x, o2.x); o2.y = fmaf(p, v2.y, o2.y); o2.z = fmaf(p, v2.z, o2.z); o2.w = fmaf(p, v2.w, o2.w);
        o3.x = fmaf(p, v3.x, o3.x); o3.y = fmaf(p, v3.y, o3.y); o3.z = fmaf(p, v3.z, o3.z); o3.w = fmaf(p, v3.w, o3.w);
    }
    float* orow = out + ((size_t)b * T_ + (size_t)(2 * (s * 64 + lane))) * DK_ + w * 16;
    *(float4*)(orow + 0)  = o0;
    *(float4*)(orow + 4)  = o1;
    *(float4*)(orow + 8)  = o2;
    *(float4*)(orow + 12) = o3;
}

extern "C" void kernel_launch(void* const* d_in, const int* in_sizes, int n_in,
                              void* d_out, int out_size, void* d_ws, size_t ws_size,
                              hipStream_t stream) {
    (void)in_sizes; (void)n_in; (void)ws_size;
    const float* x_in = (const float*)d_in[0];
    const float* P    = (const float*)d_in[1];
    const float* Wk   = (const float*)d_in[2];  // dict order: Wk before Wq
    const float* Wq   = (const float*)d_in[3];
    const float* Wv   = (const float*)d_in[4];
    float* out = (float*)d_out;
    ushort* W16 = (ushort*)d_ws;                // needs 384*1024*2 = 768 KB of workspace

    // odd output rows are zero; kernel overwrites the even rows
    hipMemsetAsync(d_out, 0, (size_t)out_size * sizeof(float), stream);
    wconv<<<dim3(192), dim3(256), 0, stream>>>(Wk, Wq, Wv, W16);
    dilattn<<<dim3(256), dim3(512), 0, stream>>>(x_in, P, W16, out);
}

// Round 3
// 435.993 us; speedup vs baseline: 1.0744x; 1.0735x over previous
//
#include <hip/hip_runtime.h>

#define B_  4
#define T_  8192
#define E_  1024
#define DK_ 128

typedef __attribute__((ext_vector_type(8))) _Float16 half8;
typedef __attribute__((ext_vector_type(4))) float float4v;

__device__ __forceinline__ half8 cvt8h(float4 a, float4 b) {
    half8 r;
    r[0] = (_Float16)a.x; r[1] = (_Float16)a.y; r[2] = (_Float16)a.z; r[3] = (_Float16)a.w;
    r[4] = (_Float16)b.x; r[5] = (_Float16)b.y; r[6] = (_Float16)b.z; r[7] = (_Float16)b.w;
    return r;
}

// One block per (b, s): fused fp16-MFMA QKV projection + fp32 attention.
// 512 threads = 8 waves. Projection: M=64 tokens, N=384 (Q|K|V), K=1024, BK=64.
// Wave w: M-tile mt=w&3, N-half=w>>2 (12 N-tiles each). 48 fp32 accumulators/wave.
// Phase-1 structure identical to the harness-verified 434 µs kernel.
// Single dispatch: odd output rows zeroed in-kernel (no memset), no workspace.
__global__ __launch_bounds__(512, 2)
void dilattn(const float* __restrict__ x_in, const float* __restrict__ P,
             const float* __restrict__ Wk, const float* __restrict__ Wq,
             const float* __restrict__ Wv, float* __restrict__ out)
{
    // 64 KB LDS, aliased:
    //  staging:   xs f16[64][72] (9216 B) | wsm f16[384][72] (55296 B)
    //  attention: A region floats [0,8192) = Q (swizzled) then V; B region [8192,16384) = K^T (rotated) then S
    __shared__ float lds_f[16384];
    ushort* xs  = (ushort*)lds_f;        // [64][72]
    ushort* wsm = xs + 64 * 72;          // [384][72]
    constexpr int A_OFF = 0;
    constexpr int B_OFF = 8192;
    constexpr int S_OFF = 8192;
    const float NORMF = 0.08838834764831845f; // 1/sqrt(128)

    const int tid  = threadIdx.x;
    const int lane = tid & 63;
    const int w    = __builtin_amdgcn_readfirstlane(tid >> 6); // 0..7
    const int b    = blockIdx.x >> 6;
    const int s    = blockIdx.x & 63;

    const int lr   = lane & 15;   // in-tile 16-dim index
    const int lg   = lane >> 4;   // k-group 0..3
    const int mt   = w & 3;       // M-tile
    const int half = w >> 2;      // N-half

    // ------- staging assignment: thread -> (row, 8-float chunk) -------
    const int c8 = tid & 7;       // chunk 0..7 (8 floats each, BK=64)
    const int xr = tid >> 3;      // row 0..63
    const float* xrow = x_in + ((size_t)b * T_ + 128 * xr + s) * E_ + c8 * 8;
    const float* wrow[6];
#pragma unroll
    for (int p = 0; p < 6; ++p) {
        const int r = xr + 64 * p; // N row 0..383: 0-127 Q, 128-255 K, 256-383 V
        const float* base = (r < 128) ? (Wq + (size_t)r * E_)
                          : (r < 256) ? (Wk + (size_t)(r - 128) * E_)
                                      : (Wv + (size_t)(r - 256) * E_);
        wrow[p] = base + c8 * 8;
    }

    float4v acc[12];
#pragma unroll
    for (int j = 0; j < 12; ++j) acc[j] = (float4v){0.f, 0.f, 0.f, 0.f};

    // ---------------- Phase 1: QKV projection via MFMA ----------------
    float4 xa0, xa1, wa0[6], wa1[6];
    // preload iter 0
    xa0 = *(const float4*)(xrow);
    xa1 = *(const float4*)(xrow + 4);
#pragma unroll
    for (int p = 0; p < 6; ++p) {
        wa0[p] = *(const float4*)(wrow[p]);
        wa1[p] = *(const float4*)(wrow[p] + 4);
    }

    for (int ki = 0; ki < 16; ++ki) {
        __syncthreads(); // previous iter's LDS reads complete
        *(half8*)&xs[xr * 72 + c8 * 8] = cvt8h(xa0, xa1);
#pragma unroll
        for (int p = 0; p < 6; ++p)
            *(half8*)&wsm[(xr + 64 * p) * 72 + c8 * 8] = cvt8h(wa0[p], wa1[p]);
        __syncthreads(); // tiles visible

        if (ki < 15) { // issue next iter's globals, overlap with MFMA
            const int k0 = (ki + 1) * 64;
            xa0 = *(const float4*)(xrow + k0);
            xa1 = *(const float4*)(xrow + k0 + 4);
#pragma unroll
            for (int p = 0; p < 6; ++p) {
                wa0[p] = *(const float4*)(wrow[p] + k0);
                wa1[p] = *(const float4*)(wrow[p] + k0 + 4);
            }
        }

#pragma unroll
        for (int kk = 0; kk < 2; ++kk) {
            const half8 afr = *(const half8*)&xs[(mt * 16 + lr) * 72 + kk * 32 + lg * 8];
#pragma unroll
            for (int j = 0; j < 12; ++j) {
                const half8 bfr = *(const half8*)&wsm[((half * 12 + j) * 16 + lr) * 72 + kk * 32 + lg * 8];
                acc[j] = __builtin_amdgcn_mfma_f32_16x16x32_f16(afr, bfr, acc[j], 0, 0, 0);
            }
        }
    }
    __syncthreads(); // last MFMA reads done; staging LDS now dead

    // ------- scatter C fragments: Q -> A region (swizzled), K -> B region (rotated K^T) -------
    // C layout: row l = mt*16 + lg*4 + reg (token), col n = nt*16 + lr (out dim)
    const int rbase = mt * 16 + lg * 4;
#pragma unroll
    for (int j = 0; j < 12; ++j) {
        const int nt = half * 12 + j;
        const int n  = nt * 16 + lr;
        if (nt < 8) {        // Q
#pragma unroll
            for (int r = 0; r < 4; ++r) {
                const int l = rbase + r;
                lds_f[A_OFF + l * 128 + ((n + 4 * l) & 127)] = acc[j][r];
            }
        } else if (nt < 16) { // K^T, rotated by m to avoid write conflicts
            const int m = n - 128;
#pragma unroll
            for (int r = 0; r < 4; ++r) {
                const int l = rbase + r;
                lds_f[B_OFF + m * 64 + ((l + m) & 63)] = acc[j][r];
            }
        } // V tiles (nt>=16) stay in registers until after phase 2a
    }
    __syncthreads();

    // ---------------- Phase 2a: S[k][q] = sum_m K[k][m]*Q[q][m]; k = lane ----------------
    // prefetch scattered P bias (L3-resident); latency hides under the K.Q loop
    float pb[8];
#pragma unroll
    for (int i = 0; i < 8; ++i)
        pb[i] = P[(size_t)lane * ((size_t)128 * T_) + (size_t)(w * 8 + i) * 128];

    float sd[8];
#pragma unroll
    for (int i = 0; i < 8; ++i) sd[i] = 0.f;

    for (int m4 = 0; m4 < 32; ++m4) {
        const int mm = 4 * m4;
        const float k0 = lds_f[B_OFF + (mm + 0) * 64 + ((lane + mm + 0) & 63)];
        const float k1 = lds_f[B_OFF + (mm + 1) * 64 + ((lane + mm + 1) & 63)];
        const float k2 = lds_f[B_OFF + (mm + 2) * 64 + ((lane + mm + 2) & 63)];
        const float k3 = lds_f[B_OFF + (mm + 3) * 64 + ((lane + mm + 3) & 63)];
#pragma unroll
        for (int i = 0; i < 8; ++i) {
            const int q = w * 8 + i; // wave-uniform -> broadcast read
            const float4 qv = *(const float4*)&lds_f[A_OFF + q * 128 + ((4 * (m4 + q)) & 127)];
            sd[i] = fmaf(k0, qv.x, fmaf(k1, qv.y, fmaf(k2, qv.z, fmaf(k3, qv.w, sd[i]))));
        }
    }
    __syncthreads(); // all Q/K^T reads done; A and B regions reusable

    // V fragments -> A region (half==1 waves hold V tiles in acc[4..11])
    if (half == 1) {
#pragma unroll
        for (int j = 4; j < 12; ++j) {
            const int nt = 12 + j;
            const int m  = nt * 16 + lr - 256; // V column 0..127
#pragma unroll
            for (int r = 0; r < 4; ++r) {
                const int l = rbase + r;
                lds_f[A_OFF + l * 128 + ((m + 4 * l) & 127)] = acc[j][r];
            }
        }
    }

    // ---------------- wave-parallel in-register softmax ----------------
    // (w,i) owns column q = w*8+i; k = lane. Fold 1/sum into stored p.
#pragma unroll
    for (int i = 0; i < 8; ++i) {
        const int q = w * 8 + i;
        const float logit = ((lane >= q ? sd[i] : -10000.f) + pb[i]) * NORMF;
        float mx = logit;
#pragma unroll
        for (int off = 32; off >= 1; off >>= 1) mx = fmaxf(mx, __shfl_xor(mx, off));
        const float ev = __expf(logit - mx);
        float sum = ev;
#pragma unroll
        for (int off = 32; off >= 1; off >>= 1) sum += __shfl_xor(sum, off);
        lds_f[S_OFF + lane * 65 + q] = ev * (1.0f / sum);
    }
    __syncthreads();

    // ---------------- Phase 2b: O[q][m] = sum_k p[k][q] * V[k][m] ----------------
    float4 o0 = {0,0,0,0}, o1 = {0,0,0,0}, o2 = {0,0,0,0}, o3 = {0,0,0,0};
    for (int k = 0; k < 64; ++k) {
        const float p = lds_f[S_OFF + k * 65 + lane];
        const int base = A_OFF + k * 128;
        const float4 v0 = *(const float4*)&lds_f[base + ((16 * w + 0  + 4 * k) & 127)];
        const float4 v1 = *(const float4*)&lds_f[base + ((16 * w + 4  + 4 * k) & 127)];
        const float4 v2 = *(const float4*)&lds_f[base + ((16 * w + 8  + 4 * k) & 127)];
        const float4 v3 = *(const float4*)&lds_f[base + ((16 * w + 12 + 4 * k) & 127)];
        o0.x = fmaf(p, v0.x, o0.x); o0.y = fmaf(p, v0.y, o0.y); o0.z = fmaf(p, v0.z, o0.z); o0.w = fmaf(p, v0.w, o0.w);
        o1.x = fmaf(p, v1.x, o1.x); o1.y = fmaf(p, v1.y, o1.y); o1.z = fmaf(p, v1.z, o1.z); o1.w = fmaf(p, v1.w, o1.w);
        o2.x = fmaf(p, v2.x, o2.x); o2.y = fmaf(p, v2.y, o2.y); o2.z = fmaf(p, v2.z, o2.z); o2.w = fmaf(p, v2.w, o2.w);
        o3.x = fmaf(p, v3.x, o3.x); o3.y = fmaf(p, v3.y, o3.y); o3.z = fmaf(p, v3.z, o3.z); o3.w = fmaf(p, v3.w, o3.w);
    }
    float* orow = out + ((size_t)b * T_ + (size_t)(2 * (s * 64 + lane))) * DK_ + w * 16;
    *(float4*)(orow + 0)  = o0;
    *(float4*)(orow + 4)  = o1;
    *(float4*)(orow + 8)  = o2;
    *(float4*)(orow + 12) = o3;
    // odd output row (token t+1) is zero: write it here instead of a memset dispatch
    const float4 z = {0.f, 0.f, 0.f, 0.f};
    *(float4*)(orow + DK_ + 0)  = z;
    *(float4*)(orow + DK_ + 4)  = z;
    *(float4*)(orow + DK_ + 8)  = z;
    *(float4*)(orow + DK_ + 12) = z;
}

extern "C" void kernel_launch(void* const* d_in, const int* in_sizes, int n_in,
                              void* d_out, int out_size, void* d_ws, size_t ws_size,
                              hipStream_t stream) {
    (void)in_sizes; (void)n_in; (void)out_size; (void)d_ws; (void)ws_size;
    const float* x_in = (const float*)d_in[0];
    const float* P    = (const float*)d_in[1];
    const float* Wk   = (const float*)d_in[2];  // dict order: Wk before Wq
    const float* Wq   = (const float*)d_in[3];
    const float* Wv   = (const float*)d_in[4];
    float* out = (float*)d_out;

    // single dispatch: kernel writes even rows and zeroes odd rows itself
    dilattn<<<dim3(256), dim3(512), 0, stream>>>(x_in, P, Wk, Wq, Wv, out);
}